// Round 2
// baseline (470.076 us; speedup 1.0000x reference)
//
#include <hip/hip_runtime.h>

// GeometricModel: two hyperbolic layers (mobius matvec + bias gyro-add + tangent tanh)
// N=32768, D=H=1024, c=1. Inputs fp32, OUTPUT fp32 (reference dtype). Internals bf16 MFMA.
//
// GEMM v3: 256x256 tile, BK=32, ring-4 LDS, counted vmcnt(8) (T4), setprio (T5),
// conflict-free XOR swizzle (T2), bijective XCD swizzle (T1),
// NEW: 2-phase K-step interleave (T3) — 16-MFMA bursts alternate with ds_read subtiles
// across barrier pairs so the matrix pipe overlaps the SIMD-mate wave's LDS service.

typedef short short8 __attribute__((ext_vector_type(8)));
typedef unsigned short u16x8 __attribute__((ext_vector_type(8)));
typedef unsigned short u16x4 __attribute__((ext_vector_type(4)));
typedef float f32x4 __attribute__((ext_vector_type(4)));

#define MAXN (1.0f - 1e-5f)

__device__ __forceinline__ float bf2f(unsigned short u) {
    return __uint_as_float(((unsigned int)u) << 16);
}
__device__ __forceinline__ unsigned short f2bf(float f) {
    unsigned int u = __float_as_uint(f);
    u += 0x7FFFu + ((u >> 16) & 1u);   // RNE
    return (unsigned short)(u >> 16);
}
__device__ __forceinline__ float wave_sum(float v) {
#pragma unroll
    for (int m = 32; m > 0; m >>= 1) v += __shfl_xor(v, m, 64);
    return v;
}
__device__ __forceinline__ float artanh_clip(float x) {
    x = fminf(fmaxf(x, -1.0f + 1e-7f), 1.0f - 1e-7f);
    return 0.5f * logf((1.0f + x) / (1.0f - x));
}

// async 16B global->LDS (LDS dest = wave-uniform base + lane*16)
__device__ __forceinline__ void gld_lds16(const unsigned short* g, unsigned short* l) {
    __builtin_amdgcn_global_load_lds(
        (const __attribute__((address_space(1))) unsigned int*)g,
        (__attribute__((address_space(3))) unsigned int*)l,
        16, 0, 0);
}

// ---- x fp32 [rows x 1024] -> bf16 copy + fp32 row norm (of original fp32) ----
__global__ __launch_bounds__(256) void cast_x_kernel(
    const float* __restrict__ X, unsigned short* __restrict__ Xb,
    float* __restrict__ xn, int K)
{
    int row = blockIdx.x * 4 + (threadIdx.x >> 6);  // one wave per row, K==1024
    int l = threadIdx.x & 63;
    const float4* xr = (const float4*)(X + (size_t)row * K);
    u16x4* xw = (u16x4*)(Xb + (size_t)row * K);
    float ss = 0.f;
#pragma unroll
    for (int i = 0; i < 4; ++i) {
        float4 v = xr[i * 64 + l];
        ss += v.x * v.x + v.y * v.y + v.z * v.z + v.w * v.w;
        u16x4 o;
        o[0] = f2bf(v.x); o[1] = f2bf(v.y); o[2] = f2bf(v.z); o[3] = f2bf(v.w);
        xw[i * 64 + l] = o;
    }
    ss = wave_sum(ss);
    if (l == 0) xn[row] = fmaxf(sqrtf(ss), 1e-15f);
}

// ---- W1,W2 fp32 -> bf16 (merged, one launch) ----
__global__ __launch_bounds__(256) void cast_w_kernel(
    const float* __restrict__ W1, unsigned short* __restrict__ W1b,
    const float* __restrict__ W2, unsigned short* __restrict__ W2b, int n4each)
{
    int i = blockIdx.x * 256 + threadIdx.x;
    const float4* src;
    u16x4* dst;
    if (i < n4each) { src = (const float4*)W1; dst = (u16x4*)W1b; }
    else            { src = (const float4*)W2; dst = (u16x4*)W2b; i -= n4each; }
    float4 v = src[i];
    u16x4 o;
    o[0] = f2bf(v.x); o[1] = f2bf(v.y); o[2] = f2bf(v.z); o[3] = f2bf(v.w);
    dst[i] = o;
}

// ---------------- C[M,Nc] = A[M,K] * B[Nc,K]^T, bf16 in/out, fp32 acc ----------------
// 256x256 tile, BK=32, 8 waves (2Mx4N -> 128x64 per wave), 512 threads.
// Ring of 4 LDS buffers (tile kt in slot kt&3); stage runs 3 K-steps ahead.
// Each K-step = 2 phases; per phase: {ds_read subtile | stage 2 gld_lds} -> barrier ->
// lgkmcnt(0) -> setprio(1) -> 16 MFMA -> setprio(0) -> barrier.
// vmcnt(8) once per K-step, AFTER phase-1 MFMA (wait hidden under compute), before the
// final barrier: at that point tiles t+2 (4 ops) + t+3 (4 ops) are in flight, t+1 landed.
#define STAGE(rs_, kt_) do {                                            \
    const int ko_ = (kt_) << 5;                                         \
    gld_lds16(Ab + ga0 + ko_, &sA[(rs_) * 8192 + c0 * 8]);              \
    gld_lds16(Ab + ga1 + ko_, &sA[(rs_) * 8192 + c1 * 8]);              \
    gld_lds16(Bb + ga0 + ko_, &sB[(rs_) * 8192 + c0 * 8]);              \
    gld_lds16(Bb + ga1 + ko_, &sB[(rs_) * 8192 + c1 * 8]);              \
} while (0)

#define KSTEP(kt_, DOSTAGE_, DOVM_, VMSTR_, DOEND_) {                               \
    const int rb_ = ((kt_) & 3) * 8192;                                             \
    const unsigned short* pa_ = &sA[rb_ + (wm + lr) * 32 + swo];                    \
    const unsigned short* pb_ = &sB[rb_ + (wn + lr) * 32 + swo];                    \
    /* ---- phase 0: B all + A m0-3; stage A-halves of kt+3 ---- */                 \
    short8 bv_[4], av_[4];                                                          \
    _Pragma("unroll")                                                               \
    for (int n_ = 0; n_ < 4; ++n_) bv_[n_] = *(const short8*)(pb_ + n_ * 512);      \
    _Pragma("unroll")                                                               \
    for (int m_ = 0; m_ < 4; ++m_) av_[m_] = *(const short8*)(pa_ + m_ * 512);      \
    if (DOSTAGE_) {                                                                 \
        const int ko_ = ((kt_) + 3) << 5;                                           \
        const int rs_ = (((kt_) + 3) & 3) * 8192;                                   \
        gld_lds16(Ab + ga0 + ko_, &sA[rs_ + c0 * 8]);                               \
        gld_lds16(Ab + ga1 + ko_, &sA[rs_ + c1 * 8]);                               \
    }                                                                               \
    __builtin_amdgcn_s_barrier();                                                   \
    asm volatile("s_waitcnt lgkmcnt(0)" ::: "memory");                              \
    __builtin_amdgcn_s_setprio(1);                                                  \
    _Pragma("unroll")                                                               \
    for (int m_ = 0; m_ < 4; ++m_)                                                  \
        _Pragma("unroll")                                                           \
        for (int n_ = 0; n_ < 4; ++n_)                                              \
            acc[m_][n_] = __builtin_amdgcn_mfma_f32_16x16x32_bf16(                  \
                av_[m_], bv_[n_], acc[m_][n_], 0, 0, 0);                            \
    __builtin_amdgcn_s_setprio(0);                                                  \
    __builtin_amdgcn_s_barrier();                                                   \
    /* ---- phase 1: A m4-7; stage B-halves of kt+3 ---- */                         \
    short8 aw_[4];                                                                  \
    _Pragma("unroll")                                                               \
    for (int m_ = 0; m_ < 4; ++m_) aw_[m_] = *(const short8*)(pa_ + (m_ + 4) * 512);\
    if (DOSTAGE_) {                                                                 \
        const int ko_ = ((kt_) + 3) << 5;                                           \
        const int rs_ = (((kt_) + 3) & 3) * 8192;                                   \
        gld_lds16(Bb + ga0 + ko_, &sB[rs_ + c0 * 8]);                               \
        gld_lds16(Bb + ga1 + ko_, &sB[rs_ + c1 * 8]);                               \
    }                                                                               \
    __builtin_amdgcn_s_barrier();                                                   \
    asm volatile("s_waitcnt lgkmcnt(0)" ::: "memory");                              \
    __builtin_amdgcn_s_setprio(1);                                                  \
    _Pragma("unroll")                                                               \
    for (int m_ = 0; m_ < 4; ++m_)                                                  \
        _Pragma("unroll")                                                           \
        for (int n_ = 0; n_ < 4; ++n_)                                              \
            acc[m_ + 4][n_] = __builtin_amdgcn_mfma_f32_16x16x32_bf16(              \
                aw_[m_], bv_[n_], acc[m_ + 4][n_], 0, 0, 0);                        \
    __builtin_amdgcn_s_setprio(0);                                                  \
    if (DOVM_) { asm volatile("s_waitcnt vmcnt(" VMSTR_ ")" ::: "memory"); }        \
    if (DOEND_) { __builtin_amdgcn_s_barrier(); }                                   \
}

__global__ __launch_bounds__(512, 2) void gemm_bt_kernel(
    const unsigned short* __restrict__ A,
    const unsigned short* __restrict__ B,
    unsigned short* __restrict__ C,
    int M, int Nc, int K)
{
    // 4 ring slots x (256 rows x 32 bf16) = 16KB per operand per slot; 128KB total
    __shared__ __align__(16) unsigned short sA[4 * 256 * 32];
    __shared__ __align__(16) unsigned short sB[4 * 256 * 32];

    const int t = threadIdx.x;       // 0..511
    const int l = t & 63;
    const int w = t >> 6;            // 0..7
    const int lr = l & 15;
    const int lq = l >> 4;

    // XCD-aware bijective swizzle (grid % 8 == 0 here: 128*4=512)
    const int nwg = gridDim.x;
    const int cpx = nwg >> 3;
    const int swz = (blockIdx.x & 7) * cpx + (blockIdx.x >> 3);
    const int nb = Nc >> 8;          // 4
    const int bm = swz / nb;
    const int bn = swz % nb;

    const unsigned short* Ab = A + (size_t)bm * 256 * K;
    const unsigned short* Bb = B + (size_t)bn * 256 * K;

    const int wm = (w >> 2) * 128;   // 0 or 128
    const int wn = (w & 3) * 64;     // 0,64,128,192

    // staging: tile = 256 rows x 64B = 1024 chunks of 16B; thread handles c0=t, c1=t+512
    // phys chunk (row, s) holds logical k-slot s ^ ((row>>1)&3)  -> pre-swizzled source
    const int c0 = t, c1 = t + 512;
    const int r0 = c0 >> 2, s0 = (c0 & 3) ^ ((r0 >> 1) & 3);
    const int r1 = c1 >> 2, s1 = (c1 & 3) ^ ((r1 >> 1) & 3);
    const size_t ga0 = (size_t)r0 * K + s0 * 8;
    const size_t ga1 = (size_t)r1 * K + s1 * 8;

    // read-side swizzled 16B slot: lq ^ ((row>>1)&3); row base is mult of 16 -> lane-const
    const int swo = (lq ^ ((lr >> 1) & 3)) * 8;

    f32x4 acc[8][4];
#pragma unroll
    for (int i = 0; i < 8; ++i)
#pragma unroll
        for (int j = 0; j < 4; ++j)
            acc[i][j] = (f32x4){0.f, 0.f, 0.f, 0.f};

    // prologue: stage tiles 0,1,2 (12 loads); wait for tile 0 (leave 8 in flight)
    STAGE(0, 0);
    STAGE(1, 1);
    STAGE(2, 2);
    asm volatile("s_waitcnt vmcnt(8)" ::: "memory");
    __builtin_amdgcn_s_barrier();

    const int NTK = K >> 5;          // 32
    int kt = 0;
#pragma unroll 1
    for (; kt < NTK - 3; ++kt) {
        KSTEP(kt, true, true, "8", true);   // stage kt+3; tiles kt+2,kt+3 stay in flight
    }
    KSTEP(kt, false, true, "4", true); ++kt;   // drain: tile NTK-1 stays in flight
    KSTEP(kt, false, true, "0", true); ++kt;   // drain fully
    KSTEP(kt, false, false, "0", false);       // last tile, no sync needed

    // C/D layout (m89-verified): col = lane&15, row = (lane>>4)*4 + reg
    unsigned short* Cb = C + (size_t)(bm * 256 + wm) * Nc + bn * 256 + wn;
#pragma unroll
    for (int i = 0; i < 8; ++i)
#pragma unroll
        for (int r = 0; r < 4; ++r) {
            unsigned short* Cr = Cb + (size_t)(i * 16 + lq * 4 + r) * Nc + lr;
#pragma unroll
            for (int j = 0; j < 4; ++j)
                Cr[j * 16] = f2bf(acc[i][j][r]);
        }
}

// ---------------- fused hyperbolic epilogue ----------------
// OUTF32=0: write bf16 (intermediate h); OUTF32=1: write fp32 (final output).
template <int OUTF32>
__global__ __launch_bounds__(256) void hyp_epilogue_kernel(
    const unsigned short* __restrict__ mx, const float* __restrict__ xn_in,
    const float* __restrict__ bvec, void* __restrict__ outp,
    float* __restrict__ xn_out, int H)
{
    int row = blockIdx.x * 4 + (threadIdx.x >> 6);  // one wave per row, H==1024
    int l = threadIdx.x & 63;
    const u16x8* mrow = (const u16x8*)(mx + (size_t)row * H);
    u16x8 mv0 = mrow[l], mv1 = mrow[64 + l];
    const float4* bf4 = (const float4*)bvec;
    float4 bq0 = bf4[l * 2], bq1 = bf4[l * 2 + 1];
    float4 bq2 = bf4[128 + l * 2], bq3 = bf4[128 + l * 2 + 1];

    float m[16], b[16];
#pragma unroll
    for (int i = 0; i < 8; ++i) { m[i] = bf2f(mv0[i]); m[8 + i] = bf2f(mv1[i]); }
    b[0] = bq0.x; b[1] = bq0.y; b[2] = bq0.z; b[3] = bq0.w;
    b[4] = bq1.x; b[5] = bq1.y; b[6] = bq1.z; b[7] = bq1.w;
    b[8] = bq2.x; b[9] = bq2.y; b[10] = bq2.z; b[11] = bq2.w;
    b[12] = bq3.x; b[13] = bq3.y; b[14] = bq3.z; b[15] = bq3.w;

    float ssm = 0.f, ssb = 0.f, dmb = 0.f;
#pragma unroll
    for (int i = 0; i < 16; ++i) {
        ssm += m[i] * m[i]; ssb += b[i] * b[i]; dmb += m[i] * b[i];
    }
    ssm = wave_sum(ssm); ssb = wave_sum(ssb); dmb = wave_sum(dmb);

    float mxn = fmaxf(sqrtf(ssm), 1e-15f);
    float bn  = fmaxf(sqrtf(ssb), 1e-15f);
    float xn  = xn_in[row];

    // gyro_matvec tail + proj
    float tt = tanhf(mxn / xn * artanh_clip(xn));
    float rnorm = fabsf(tt);
    float pr = (rnorm > MAXN) ? (MAXN / rnorm) : 1.0f;
    float resScale = tt * pr / mxn;            // res_i = resScale * m[i]
    float rn = fminf(rnorm, MAXN);
    float x2 = rn * rn;

    // hyp_bias = proj(expmap0(b))
    float tb = tanhf(bn);
    float hbn = fabsf(tb);
    float pb = (hbn > MAXN) ? (MAXN / hbn) : 1.0f;
    float hscale = (tb / bn) * pb;
    float hn = fminf(hbn, MAXN);
    float y2 = hn * hn;

    // gyro_add(res, hb): z_i = fA*m[i] + fB*b[i]
    float xy = resScale * hscale * dmb;
    float ca = 1.0f + 2.0f * xy + y2;
    float cb = 1.0f - x2;
    float den = fmaxf(1.0f + 2.0f * xy + x2 * y2, 1e-15f);
    float fA = ca * resScale / den;
    float fB = cb * hscale / den;

    // ||z||^2 analytic from (ssm, ssb, dmb)
    float ssz = fA * fA * ssm + 2.0f * fA * fB * dmb + fB * fB * ssb;
    float zn = fmaxf(sqrtf(fmaxf(ssz, 0.0f)), 1e-15f);
    float pz = (zn > MAXN) ? (MAXN / zn) : 1.0f;
    float n2 = fmaxf(fminf(zn, MAXN), 1e-15f);
    float g = (artanh_clip(n2) / n2) * pz;     // logmap0 scale incl. proj

    // tangent tanh, then expmap0 + proj
    float u[16];
    float ssu = 0.f;
#pragma unroll
    for (int i = 0; i < 16; ++i) {
        float zi = fA * m[i] + fB * b[i];
        u[i] = tanhf(g * zi);
        ssu += u[i] * u[i];
    }
    ssu = wave_sum(ssu);
    float un = fmaxf(sqrtf(ssu), 1e-15f);
    float te = tanhf(un);
    float on = fabsf(te);
    float po = (on > MAXN) ? (MAXN / on) : 1.0f;
    float os = (te / un) * po;

    if (OUTF32) {
        float* of = (float*)outp + (size_t)row * H;
        float4* of4 = (float4*)of;
        float4 a0, a1, a2, a3;
        a0.x = os * u[0];  a0.y = os * u[1];  a0.z = os * u[2];  a0.w = os * u[3];
        a1.x = os * u[4];  a1.y = os * u[5];  a1.z = os * u[6];  a1.w = os * u[7];
        a2.x = os * u[8];  a2.y = os * u[9];  a2.z = os * u[10]; a2.w = os * u[11];
        a3.x = os * u[12]; a3.y = os * u[13]; a3.z = os * u[14]; a3.w = os * u[15];
        of4[l * 2] = a0; of4[l * 2 + 1] = a1;
        of4[128 + l * 2] = a2; of4[128 + l * 2 + 1] = a3;
    } else {
        u16x8 o0, o1;
#pragma unroll
        for (int i = 0; i < 8; ++i) { o0[i] = f2bf(os * u[i]); o1[i] = f2bf(os * u[8 + i]); }
        u16x8* orow = (u16x8*)((unsigned short*)outp + (size_t)row * H);
        orow[l] = o0; orow[64 + l] = o1;
    }
    // next layer's _norm(h) = min(|tanh(un)|, maxnorm), analytic (pre-rounding)
    if (l == 0) xn_out[row] = fmaxf(fminf(on, MAXN), 1e-15f);
}

extern "C" void kernel_launch(void* const* d_in, const int* in_sizes, int n_in,
                              void* d_out, int out_size, void* d_ws, size_t ws_size,
                              hipStream_t stream)
{
    const float* x  = (const float*)d_in[0];
    const float* W1 = (const float*)d_in[1];
    const float* b1 = (const float*)d_in[2];
    const float* W2 = (const float*)d_in[3];
    const float* b2 = (const float*)d_in[4];

    const int H = in_sizes[2];       // 1024
    const int D = in_sizes[1] / H;   // 1024
    const int N = in_sizes[0] / D;   // 32768

    // d_out is fp32 [N*H] = 128MB; its first 64MB doubles as bf16 staging for xb/h.
    unsigned short* stage = (unsigned short*)d_out;   // bf16 x-copy, then bf16 h
    float* outf = (float*)d_out;

    // ws: mx bf16 [N*H] (64MB) | W1b (2MB) | W2b (2MB) | xn1 | xn2
    unsigned short* mxb = (unsigned short*)d_ws;
    unsigned short* W1b = mxb + (size_t)N * H;
    unsigned short* W2b = W1b + (size_t)H * D;
    float* xn1 = (float*)(W2b + (size_t)H * H);
    float* xn2 = xn1 + N;

    dim3 blk(256);
    dim3 gblk(512);
    const int gemm_grid = (N / 256) * (H / 256);   // 128*4 = 512, %8==0 for XCD swizzle
    const int n4w = H * D / 4;                     // per-matrix float4 count

    cast_x_kernel<<<N / 4, blk, 0, stream>>>(x, stage, xn1, D);
    cast_w_kernel<<<(2 * n4w + 255) / 256, blk, 0, stream>>>(W1, W1b, W2, W2b, n4w);
    // layer 1: mx = xb @ W1^T; epilogue writes bf16 h over the xb staging area
    gemm_bt_kernel<<<gemm_grid, gblk, 0, stream>>>(stage, W1b, mxb, N, H, D);
    hyp_epilogue_kernel<0><<<N / 4, blk, 0, stream>>>(mxb, xn1, b1, stage, xn2, H);
    // layer 2: mx2 = h @ W2^T; final epilogue writes fp32 over the full d_out
    gemm_bt_kernel<<<gemm_grid, gblk, 0, stream>>>(stage, W2b, mxb, N, H, H);
    hyp_epilogue_kernel<1><<<N / 4, blk, 0, stream>>>(mxb, xn2, b2, outf, xn1, H);
}

// Round 3
// 456.958 us; speedup vs baseline: 1.0287x; 1.0287x over previous
//
#include <hip/hip_runtime.h>

// GeometricModel: two hyperbolic layers (mobius matvec + bias gyro-add + tangent tanh)
// N=32768, D=H=1024, c=1. Inputs fp32, OUTPUT fp32 (reference dtype). Internals bf16 MFMA.
//
// GEMM v4: 256x256 tile, BK=32, ring-4 LDS, counted vmcnt(4) (T4), setprio (T5),
// conflict-free XOR swizzle (T2), bijective XCD swizzle (T1),
// NEW: register double-buffered fragment prefetch — ds_read tile t+1's frags into the
// alternate reg set BEFORE the MFMA burst on tile t (no dependency), so the LDS pipe
// streams next-tile fragments while the matrix pipe runs. One barrier per K-step.

typedef short short8 __attribute__((ext_vector_type(8)));
typedef unsigned short u16x8 __attribute__((ext_vector_type(8)));
typedef unsigned short u16x4 __attribute__((ext_vector_type(4)));
typedef float f32x4 __attribute__((ext_vector_type(4)));

#define MAXN (1.0f - 1e-5f)

__device__ __forceinline__ float bf2f(unsigned short u) {
    return __uint_as_float(((unsigned int)u) << 16);
}
__device__ __forceinline__ unsigned short f2bf(float f) {
    unsigned int u = __float_as_uint(f);
    u += 0x7FFFu + ((u >> 16) & 1u);   // RNE
    return (unsigned short)(u >> 16);
}
__device__ __forceinline__ float wave_sum(float v) {
#pragma unroll
    for (int m = 32; m > 0; m >>= 1) v += __shfl_xor(v, m, 64);
    return v;
}
__device__ __forceinline__ float artanh_clip(float x) {
    x = fminf(fmaxf(x, -1.0f + 1e-7f), 1.0f - 1e-7f);
    return 0.5f * logf((1.0f + x) / (1.0f - x));
}

// async 16B global->LDS (LDS dest = wave-uniform base + lane*16)
__device__ __forceinline__ void gld_lds16(const unsigned short* g, unsigned short* l) {
    __builtin_amdgcn_global_load_lds(
        (const __attribute__((address_space(1))) unsigned int*)g,
        (__attribute__((address_space(3))) unsigned int*)l,
        16, 0, 0);
}

// ---- x fp32 [rows x 1024] -> bf16 copy + fp32 row norm (of original fp32) ----
__global__ __launch_bounds__(256) void cast_x_kernel(
    const float* __restrict__ X, unsigned short* __restrict__ Xb,
    float* __restrict__ xn, int K)
{
    int row = blockIdx.x * 4 + (threadIdx.x >> 6);  // one wave per row, K==1024
    int l = threadIdx.x & 63;
    const float4* xr = (const float4*)(X + (size_t)row * K);
    u16x4* xw = (u16x4*)(Xb + (size_t)row * K);
    float ss = 0.f;
#pragma unroll
    for (int i = 0; i < 4; ++i) {
        float4 v = xr[i * 64 + l];
        ss += v.x * v.x + v.y * v.y + v.z * v.z + v.w * v.w;
        u16x4 o;
        o[0] = f2bf(v.x); o[1] = f2bf(v.y); o[2] = f2bf(v.z); o[3] = f2bf(v.w);
        xw[i * 64 + l] = o;
    }
    ss = wave_sum(ss);
    if (l == 0) xn[row] = fmaxf(sqrtf(ss), 1e-15f);
}

// ---- W1,W2 fp32 -> bf16 (merged, one launch) ----
__global__ __launch_bounds__(256) void cast_w_kernel(
    const float* __restrict__ W1, unsigned short* __restrict__ W1b,
    const float* __restrict__ W2, unsigned short* __restrict__ W2b, int n4each)
{
    int i = blockIdx.x * 256 + threadIdx.x;
    const float4* src;
    u16x4* dst;
    if (i < n4each) { src = (const float4*)W1; dst = (u16x4*)W1b; }
    else            { src = (const float4*)W2; dst = (u16x4*)W2b; i -= n4each; }
    float4 v = src[i];
    u16x4 o;
    o[0] = f2bf(v.x); o[1] = f2bf(v.y); o[2] = f2bf(v.z); o[3] = f2bf(v.w);
    dst[i] = o;
}

// ---------------- C[M,Nc] = A[M,K] * B[Nc,K]^T, bf16 in/out, fp32 acc ----------------
// 256x256 tile, BK=32, 8 waves (2Mx4N -> 128x64 per wave), 512 threads.
// Ring of 4 LDS buffers (tile kt in slot kt&3); stage runs 3 K-steps ahead.
// Per K-step t: STAGE(t+3) | ds_read frags(t+1) -> alt reg set | 32 MFMA on cur set
//               | vmcnt(4) | barrier
// Residency ledger: end-of-step vmcnt(4)+barrier => tiles <= t+2 collectively resident,
// so prefetching t+1's frags during step t is always safe. WAR on ring slots: reads of
// tile t complete before their MFMAs (step t) which precede the barrier; slot (t)&3 is
// rewritten (as tile t+4) at step t+1, after that barrier.
#define STAGE(rs_, kt_) do {                                            \
    const int ko_ = (kt_) << 5;                                         \
    gld_lds16(Ab + ga0 + ko_, &sA[(rs_) * 8192 + c0 * 8]);              \
    gld_lds16(Ab + ga1 + ko_, &sA[(rs_) * 8192 + c1 * 8]);              \
    gld_lds16(Bb + ga0 + ko_, &sB[(rs_) * 8192 + c0 * 8]);              \
    gld_lds16(Bb + ga1 + ko_, &sB[(rs_) * 8192 + c1 * 8]);              \
} while (0)

#define LDFRAG(FA_, FB_, kt_) do {                                                  \
    const int rb_ = ((kt_) & 3) * 8192;                                             \
    const unsigned short* pa_ = &sA[rb_ + (wm + lr) * 32 + swo];                    \
    const unsigned short* pb_ = &sB[rb_ + (wn + lr) * 32 + swo];                    \
    _Pragma("unroll")                                                               \
    for (int m_ = 0; m_ < 8; ++m_) FA_[m_] = *(const short8*)(pa_ + m_ * 512);      \
    _Pragma("unroll")                                                               \
    for (int n_ = 0; n_ < 4; ++n_) FB_[n_] = *(const short8*)(pb_ + n_ * 512);      \
} while (0)

#define MFMAB(FA_, FB_)                                                             \
    _Pragma("unroll")                                                               \
    for (int m_ = 0; m_ < 8; ++m_)                                                  \
        _Pragma("unroll")                                                           \
        for (int n_ = 0; n_ < 4; ++n_)                                              \
            acc[m_][n_] = __builtin_amdgcn_mfma_f32_16x16x32_bf16(                  \
                FA_[m_], FB_[n_], acc[m_][n_], 0, 0, 0);

#define PSTEP(kt_, FAC_, FBC_, FAN_, FBN_, DOSTAGE_, DOPF_, DOVM_, VMSTR_, DOBAR_) {\
    if (DOSTAGE_) { STAGE((((kt_) + 3) & 3), (kt_) + 3); }                          \
    if (DOPF_) { LDFRAG(FAN_, FBN_, (kt_) + 1); }                                   \
    __builtin_amdgcn_s_setprio(1);                                                  \
    MFMAB(FAC_, FBC_);                                                              \
    __builtin_amdgcn_s_setprio(0);                                                  \
    if (DOVM_) { asm volatile("s_waitcnt vmcnt(" VMSTR_ ")" ::: "memory"); }        \
    if (DOBAR_) { __builtin_amdgcn_s_barrier(); }                                   \
}

__global__ __launch_bounds__(512, 2) void gemm_bt_kernel(
    const unsigned short* __restrict__ A,
    const unsigned short* __restrict__ B,
    unsigned short* __restrict__ C,
    int M, int Nc, int K)
{
    // 4 ring slots x (256 rows x 32 bf16) = 16KB per operand per slot; 128KB total
    __shared__ __align__(16) unsigned short sA[4 * 256 * 32];
    __shared__ __align__(16) unsigned short sB[4 * 256 * 32];

    const int t = threadIdx.x;       // 0..511
    const int l = t & 63;
    const int w = t >> 6;            // 0..7
    const int lr = l & 15;
    const int lq = l >> 4;

    // XCD-aware bijective swizzle (grid % 8 == 0 here: 128*4=512)
    const int nwg = gridDim.x;
    const int cpx = nwg >> 3;
    const int swz = (blockIdx.x & 7) * cpx + (blockIdx.x >> 3);
    const int nb = Nc >> 8;          // 4
    const int bm = swz / nb;
    const int bn = swz % nb;

    const unsigned short* Ab = A + (size_t)bm * 256 * K;
    const unsigned short* Bb = B + (size_t)bn * 256 * K;

    const int wm = (w >> 2) * 128;   // 0 or 128
    const int wn = (w & 3) * 64;     // 0,64,128,192

    // staging: tile = 256 rows x 64B = 1024 chunks of 16B; thread handles c0=t, c1=t+512
    // phys chunk (row, s) holds logical k-slot s ^ ((row>>1)&3)  -> pre-swizzled source
    const int c0 = t, c1 = t + 512;
    const int r0 = c0 >> 2, s0 = (c0 & 3) ^ ((r0 >> 1) & 3);
    const int r1 = c1 >> 2, s1 = (c1 & 3) ^ ((r1 >> 1) & 3);
    const size_t ga0 = (size_t)r0 * K + s0 * 8;
    const size_t ga1 = (size_t)r1 * K + s1 * 8;

    // read-side swizzled 16B slot: lq ^ ((row>>1)&3); row base is mult of 16 -> lane-const
    const int swo = (lq ^ ((lr >> 1) & 3)) * 8;

    f32x4 acc[8][4];
#pragma unroll
    for (int i = 0; i < 8; ++i)
#pragma unroll
        for (int j = 0; j < 4; ++j)
            acc[i][j] = (f32x4){0.f, 0.f, 0.f, 0.f};

    // prologue: stage tiles 0,1,2 (12 loads); vmcnt(4) -> tiles 0,1 resident
    STAGE(0, 0);
    STAGE(1, 1);
    STAGE(2, 2);
    asm volatile("s_waitcnt vmcnt(4)" ::: "memory");
    __builtin_amdgcn_s_barrier();

    short8 fa0[8], fb0[4], fa1[8], fb1[4];
    LDFRAG(fa0, fb0, 0);

    const int NTK = K >> 5;          // 32
    int kt = 0;
#pragma unroll 1
    for (; kt < NTK - 4; kt += 2) {
        PSTEP(kt,     fa0, fb0, fa1, fb1, true, true, true, "4", true);
        PSTEP(kt + 1, fa1, fb1, fa0, fb0, true, true, true, "4", true);
    }
    // kt == NTK-4 here (NTK even). Stage the final tile NTK-1, then drain.
    PSTEP(NTK - 4, fa0, fb0, fa1, fb1, true,  true,  true,  "4", true);
    PSTEP(NTK - 3, fa1, fb1, fa0, fb0, false, true,  true,  "0", true);
    PSTEP(NTK - 2, fa0, fb0, fa1, fb1, false, true,  false, "0", false);
    PSTEP(NTK - 1, fa1, fb1, fa0, fb0, false, false, false, "0", false);

    // C/D layout (m89-verified): col = lane&15, row = (lane>>4)*4 + reg
    unsigned short* Cb = C + (size_t)(bm * 256 + wm) * Nc + bn * 256 + wn;
#pragma unroll
    for (int i = 0; i < 8; ++i)
#pragma unroll
        for (int r = 0; r < 4; ++r) {
            unsigned short* Cr = Cb + (size_t)(i * 16 + lq * 4 + r) * Nc + lr;
#pragma unroll
            for (int j = 0; j < 4; ++j)
                Cr[j * 16] = f2bf(acc[i][j][r]);
        }
}

// ---------------- fused hyperbolic epilogue ----------------
// OUTF32=0: write bf16 (intermediate h); OUTF32=1: write fp32 (final output).
template <int OUTF32>
__global__ __launch_bounds__(256) void hyp_epilogue_kernel(
    const unsigned short* __restrict__ mx, const float* __restrict__ xn_in,
    const float* __restrict__ bvec, void* __restrict__ outp,
    float* __restrict__ xn_out, int H)
{
    int row = blockIdx.x * 4 + (threadIdx.x >> 6);  // one wave per row, H==1024
    int l = threadIdx.x & 63;
    const u16x8* mrow = (const u16x8*)(mx + (size_t)row * H);
    u16x8 mv0 = mrow[l], mv1 = mrow[64 + l];
    const float4* bf4 = (const float4*)bvec;
    float4 bq0 = bf4[l * 2], bq1 = bf4[l * 2 + 1];
    float4 bq2 = bf4[128 + l * 2], bq3 = bf4[128 + l * 2 + 1];

    float m[16], b[16];
#pragma unroll
    for (int i = 0; i < 8; ++i) { m[i] = bf2f(mv0[i]); m[8 + i] = bf2f(mv1[i]); }
    b[0] = bq0.x; b[1] = bq0.y; b[2] = bq0.z; b[3] = bq0.w;
    b[4] = bq1.x; b[5] = bq1.y; b[6] = bq1.z; b[7] = bq1.w;
    b[8] = bq2.x; b[9] = bq2.y; b[10] = bq2.z; b[11] = bq2.w;
    b[12] = bq3.x; b[13] = bq3.y; b[14] = bq3.z; b[15] = bq3.w;

    float ssm = 0.f, ssb = 0.f, dmb = 0.f;
#pragma unroll
    for (int i = 0; i < 16; ++i) {
        ssm += m[i] * m[i]; ssb += b[i] * b[i]; dmb += m[i] * b[i];
    }
    ssm = wave_sum(ssm); ssb = wave_sum(ssb); dmb = wave_sum(dmb);

    float mxn = fmaxf(sqrtf(ssm), 1e-15f);
    float bn  = fmaxf(sqrtf(ssb), 1e-15f);
    float xn  = xn_in[row];

    // gyro_matvec tail + proj
    float tt = tanhf(mxn / xn * artanh_clip(xn));
    float rnorm = fabsf(tt);
    float pr = (rnorm > MAXN) ? (MAXN / rnorm) : 1.0f;
    float resScale = tt * pr / mxn;            // res_i = resScale * m[i]
    float rn = fminf(rnorm, MAXN);
    float x2 = rn * rn;

    // hyp_bias = proj(expmap0(b))
    float tb = tanhf(bn);
    float hbn = fabsf(tb);
    float pb = (hbn > MAXN) ? (MAXN / hbn) : 1.0f;
    float hscale = (tb / bn) * pb;
    float hn = fminf(hbn, MAXN);
    float y2 = hn * hn;

    // gyro_add(res, hb): z_i = fA*m[i] + fB*b[i]
    float xy = resScale * hscale * dmb;
    float ca = 1.0f + 2.0f * xy + y2;
    float cb = 1.0f - x2;
    float den = fmaxf(1.0f + 2.0f * xy + x2 * y2, 1e-15f);
    float fA = ca * resScale / den;
    float fB = cb * hscale / den;

    // ||z||^2 analytic from (ssm, ssb, dmb)
    float ssz = fA * fA * ssm + 2.0f * fA * fB * dmb + fB * fB * ssb;
    float zn = fmaxf(sqrtf(fmaxf(ssz, 0.0f)), 1e-15f);
    float pz = (zn > MAXN) ? (MAXN / zn) : 1.0f;
    float n2 = fmaxf(fminf(zn, MAXN), 1e-15f);
    float g = (artanh_clip(n2) / n2) * pz;     // logmap0 scale incl. proj

    // tangent tanh, then expmap0 + proj
    float u[16];
    float ssu = 0.f;
#pragma unroll
    for (int i = 0; i < 16; ++i) {
        float zi = fA * m[i] + fB * b[i];
        u[i] = tanhf(g * zi);
        ssu += u[i] * u[i];
    }
    ssu = wave_sum(ssu);
    float un = fmaxf(sqrtf(ssu), 1e-15f);
    float te = tanhf(un);
    float on = fabsf(te);
    float po = (on > MAXN) ? (MAXN / on) : 1.0f;
    float os = (te / un) * po;

    if (OUTF32) {
        float* of = (float*)outp + (size_t)row * H;
        float4* of4 = (float4*)of;
        float4 a0, a1, a2, a3;
        a0.x = os * u[0];  a0.y = os * u[1];  a0.z = os * u[2];  a0.w = os * u[3];
        a1.x = os * u[4];  a1.y = os * u[5];  a1.z = os * u[6];  a1.w = os * u[7];
        a2.x = os * u[8];  a2.y = os * u[9];  a2.z = os * u[10]; a2.w = os * u[11];
        a3.x = os * u[12]; a3.y = os * u[13]; a3.z = os * u[14]; a3.w = os * u[15];
        of4[l * 2] = a0; of4[l * 2 + 1] = a1;
        of4[128 + l * 2] = a2; of4[128 + l * 2 + 1] = a3;
    } else {
        u16x8 o0, o1;
#pragma unroll
        for (int i = 0; i < 8; ++i) { o0[i] = f2bf(os * u[i]); o1[i] = f2bf(os * u[8 + i]); }
        u16x8* orow = (u16x8*)((unsigned short*)outp + (size_t)row * H);
        orow[l] = o0; orow[64 + l] = o1;
    }
    // next layer's _norm(h) = min(|tanh(un)|, maxnorm), analytic (pre-rounding)
    if (l == 0) xn_out[row] = fmaxf(fminf(on, MAXN), 1e-15f);
}

extern "C" void kernel_launch(void* const* d_in, const int* in_sizes, int n_in,
                              void* d_out, int out_size, void* d_ws, size_t ws_size,
                              hipStream_t stream)
{
    const float* x  = (const float*)d_in[0];
    const float* W1 = (const float*)d_in[1];
    const float* b1 = (const float*)d_in[2];
    const float* W2 = (const float*)d_in[3];
    const float* b2 = (const float*)d_in[4];

    const int H = in_sizes[2];       // 1024
    const int D = in_sizes[1] / H;   // 1024
    const int N = in_sizes[0] / D;   // 32768

    // d_out is fp32 [N*H] = 128MB; its first 64MB doubles as bf16 staging for xb/h.
    unsigned short* stage = (unsigned short*)d_out;   // bf16 x-copy, then bf16 h
    float* outf = (float*)d_out;

    // ws: mx bf16 [N*H] (64MB) | W1b (2MB) | W2b (2MB) | xn1 | xn2
    unsigned short* mxb = (unsigned short*)d_ws;
    unsigned short* W1b = mxb + (size_t)N * H;
    unsigned short* W2b = W1b + (size_t)H * D;
    float* xn1 = (float*)(W2b + (size_t)H * H);
    float* xn2 = xn1 + N;

    dim3 blk(256);
    dim3 gblk(512);
    const int gemm_grid = (N / 256) * (H / 256);   // 128*4 = 512, %8==0 for XCD swizzle
    const int n4w = H * D / 4;                     // per-matrix float4 count

    cast_x_kernel<<<N / 4, blk, 0, stream>>>(x, stage, xn1, D);
    cast_w_kernel<<<(2 * n4w + 255) / 256, blk, 0, stream>>>(W1, W1b, W2, W2b, n4w);
    // layer 1: mx = xb @ W1^T; epilogue writes bf16 h over the xb staging area
    gemm_bt_kernel<<<gemm_grid, gblk, 0, stream>>>(stage, W1b, mxb, N, H, D);
    hyp_epilogue_kernel<0><<<N / 4, blk, 0, stream>>>(mxb, xn1, b1, stage, xn2, H);
    // layer 2: mx2 = h @ W2^T; final epilogue writes fp32 over the full d_out
    gemm_bt_kernel<<<gemm_grid, gblk, 0, stream>>>(stage, W2b, mxb, N, H, H);
    hyp_epilogue_kernel<1><<<N / 4, blk, 0, stream>>>(mxb, xn2, b2, outf, xn1, H);
}